// Round 12
// baseline (220.077 us; speedup 1.0000x reference)
//
#include <hip/hip_runtime.h>
#include <hip/hip_fp16.h>

#define NN 100000
#define NE 1600000

// Radix partition params: buckets of 256 nodes
#define K_B 391                          // ceil(NN/256) buckets
#define B_P 256                          // partition blocks
#define CH  ((NE + B_P - 1) / B_P)       // 6250 edges per partition block
#define NSC (K_B * B_P)                  // histogram table size (100096)
#define NBLK_H ((NSC + 1023) / 1024)     // 98 blocks for hist scan
#define GW2_GRID 2048                    // grid-stride blocks for k_gemmW2

// ---------------------------------------------------------------------------
// edge_index dtype detection: if int64 (values < 2^31), odd 32-bit words are 0.
__global__ void k_detect(const unsigned int* w, int* flag) {
    int i = blockIdx.x * blockDim.x + threadIdx.x;
    if (i < 65536 && w[2 * i + 1] != 0u) *flag = 1;
}

__device__ __forceinline__ void load_edge(const void* ei, int is32, int e,
                                          int& s, int& d) {
    if (is32) {
        const int* p = (const int*)ei;
        s = p[e]; d = p[NE + e];
    } else {
        const long long* p = (const long long*)ei;
        s = (int)p[e]; d = (int)p[NE + e];
    }
}

// ---------------------------------------------------------------------------
// P1: per-block histogram of dst>>8 over this block's edge chunk
__global__ __launch_bounds__(256) void k_hist(const void* ei, const int* __restrict__ flag,
                                              int* __restrict__ hist) {
    __shared__ int h[K_B];
    for (int i = threadIdx.x; i < K_B; i += 256) h[i] = 0;
    __syncthreads();
    int b = blockIdx.x;
    int is32 = *flag;
    int e0 = b * CH, e1 = min(e0 + CH, NE);
    for (int e = e0 + threadIdx.x; e < e1; e += 256) {
        int d = is32 ? ((const int*)ei)[NE + e] : (int)((const long long*)ei)[NE + e];
        atomicAdd(&h[d >> 8], 1);
    }
    __syncthreads();
    for (int i = threadIdx.x; i < K_B; i += 256) hist[i * B_P + b] = h[i];
}

// ---------------------------------------------------------------------------
// Generalized hierarchical exclusive scan (3 kernels), n <= 128*1024
__global__ __launch_bounds__(256) void k_gscan1(const int* __restrict__ in,
                                                int* __restrict__ ex,
                                                int* __restrict__ bsum, int n) {
    __shared__ int lds[256];
    int b = blockIdx.x, t = threadIdx.x;
    int base = b * 1024 + t * 4;
    int v[4];
#pragma unroll
    for (int k = 0; k < 4; ++k) { int i = base + k; v[k] = (i < n) ? in[i] : 0; }
    int s = v[0] + v[1] + v[2] + v[3];
    lds[t] = s;
    __syncthreads();
    for (int off = 1; off < 256; off <<= 1) {
        int tmp = (t >= off) ? lds[t - off] : 0;
        __syncthreads();
        lds[t] += tmp;
        __syncthreads();
    }
    int run = lds[t] - s;
#pragma unroll
    for (int k = 0; k < 4; ++k) {
        int i = base + k;
        if (i < n) ex[i] = run;
        run += v[k];
    }
    if (t == 255) bsum[b] = lds[255];
}

__global__ __launch_bounds__(128) void k_gscan2(int* bsum, int nblk) {
    __shared__ int lds[128];
    int t = threadIdx.x;
    int v = (t < nblk) ? bsum[t] : 0;
    lds[t] = v;
    __syncthreads();
    for (int off = 1; off < 128; off <<= 1) {
        int tmp = (t >= off) ? lds[t - off] : 0;
        __syncthreads();
        lds[t] += tmp;
        __syncthreads();
    }
    if (t < nblk) bsum[t] = lds[t] - v;  // exclusive
}

__global__ void k_gscan3(int* __restrict__ ex, const int* __restrict__ bsum, int n) {
    int i = blockIdx.x * blockDim.x + threadIdx.x;
    if (i < n) ex[i] += bsum[i >> 10];
}

// ---------------------------------------------------------------------------
// P3: partition edges into per-(block,bucket) contiguous runs (LDS cursors only)
__global__ __launch_bounds__(256) void k_part(const void* ei, const int* __restrict__ flag,
                                              const int* __restrict__ off,
                                              unsigned* __restrict__ packed) {
    __shared__ int cur[K_B];
    int b = blockIdx.x;
    for (int i = threadIdx.x; i < K_B; i += 256) cur[i] = off[i * B_P + b];
    __syncthreads();
    int is32 = *flag;
    int e0 = b * CH, e1 = min(e0 + CH, NE);
    for (int e = e0 + threadIdx.x; e < e1; e += 256) {
        int s, d;
        load_edge(ei, is32, e, s, d);
        int k = d >> 8;
        int pos = atomicAdd(&cur[k], 1);
        packed[pos] = ((unsigned)s << 8) | (unsigned)(d & 255);
    }
}

// ---------------------------------------------------------------------------
// P4 fused per-bucket: count -> local scan -> rowptr/dinv/xn -> place ssrc.
__global__ __launch_bounds__(256) void k_bucket(const int* __restrict__ off,
                                                const unsigned* __restrict__ packed,
                                                const float* __restrict__ x,
                                                int* __restrict__ rowptr,
                                                float* __restrict__ dinv,
                                                float2* __restrict__ xn,
                                                int* __restrict__ ssrc) {
    __shared__ int cnt[256];
    __shared__ int excl[256];
    int k = blockIdx.x, t = threadIdx.x;
    cnt[t] = 0;
    __syncthreads();
    int g0 = off[k * B_P];
    int g1 = (k == K_B - 1) ? NE : off[(k + 1) * B_P];
    for (int i = g0 + t; i < g1; i += 256)
        atomicAdd(&cnt[packed[i] & 255u], 1);
    __syncthreads();
    int v = cnt[t];
    excl[t] = v;
    __syncthreads();
    for (int o = 1; o < 256; o <<= 1) {
        int tmp = (t >= o) ? excl[t - o] : 0;
        __syncthreads();
        excl[t] += tmp;
        __syncthreads();
    }
    int rb = g0 + excl[t] - v;  // rowptr[n]: bucket start + local exclusive prefix
    int n = (k << 8) + t;
    if (n < NN) {
        rowptr[n] = rb;
        float di = rsqrtf((float)(v + 1));  // +1 self-loop
        dinv[n] = di;
        float2 xv = ((const float2*)x)[n];
        xn[n] = make_float2(xv.x * di, xv.y * di);
    }
    if (k == K_B - 1 && t == 0) rowptr[NN] = NE;
    __syncthreads();
    excl[t] = rb;   // reuse as row base for placement
    cnt[t] = 0;
    __syncthreads();
    for (int i = g0 + t; i < g1; i += 256) {
        unsigned pk = packed[i];
        int dl = pk & 255u;
        int r = atomicAdd(&cnt[dl], 1);
        ssrc[excl[dl] + r] = (int)(pk >> 8);
    }
}

// ---------------------------------------------------------------------------
// Layer 1 fused: lane-parallel agg of xn (2-wide) + 2->64 transform + bias +
// ReLU + next-layer dinv scale.  hn1[n][j] = fp32( dinv[n]*relu(...) )
// (fp32 output: hn1 is only STREAMED by k_gemmW2 now, never gathered — keep
// full precision; the gathered tensor tn1 is the fp16 one.)
__global__ __launch_bounds__(256) void k_layer1(const int* __restrict__ rowptr,
                                                const int* __restrict__ ssrc,
                                                const float2* __restrict__ xn,
                                                const float* __restrict__ dinv,
                                                const float* __restrict__ W1,
                                                const float* __restrict__ b1,
                                                float* __restrict__ hn1) {
    int node = blockIdx.x * 4 + (threadIdx.x >> 6);
    if (node >= NN) return;
    int lane = threadIdx.x & 63;
    int s0 = rowptr[node], e0 = rowptr[node + 1];
    float ax = 0.f, ay = 0.f;
    for (int i = s0 + lane; i < e0; i += 64) {
        float2 v = xn[ssrc[i]];
        ax += v.x; ay += v.y;
    }
#pragma unroll
    for (int m = 1; m < 64; m <<= 1) {
        ax += __shfl_xor(ax, m, 64);
        ay += __shfl_xor(ay, m, 64);
    }
    float2 a = xn[node];  // self loop
    ax += a.x; ay += a.y;
    float di = dinv[node];
    ax *= di; ay *= di;
    float v = fmaf(ax, W1[lane], fmaf(ay, W1[64 + lane], b1[lane]));
    hn1[(size_t)node * 64 + lane] = di * fmaxf(v, 0.f);
}

// ---------------------------------------------------------------------------
// Dense transform: tn1 = hn1 @ W2, fp16 out.  Linearity: aggregate(h)@W2 ==
// aggregate(h@W2), so the 64x64 GEMM runs ONCE per node here (register-held
// W2 column per lane, zero LDS) instead of inside the gather kernel where its
// per-node LDS reads were the measured bottleneck (~80us of LDS pipe).
__global__ __launch_bounds__(256) void k_gemmW2(const float* __restrict__ hn1,
                                                const float* __restrict__ W2,
                                                __half* __restrict__ tn1) {
    int w = threadIdx.x >> 6, lane = threadIdx.x & 63;
    float wc[64];
#pragma unroll
    for (int k = 0; k < 64; ++k) wc[k] = W2[k * 64 + lane];  // column j=lane
    for (int node = blockIdx.x * 4 + w; node < NN; node += GW2_GRID * 4) {
        const float4* rp = (const float4*)(hn1 + (size_t)node * 64);
        float o0 = 0.f, o1 = 0.f, o2 = 0.f, o3 = 0.f;
#pragma unroll
        for (int c = 0; c < 4; ++c) {
            float4 r0 = rp[4 * c + 0];   // wave-uniform addresses (broadcast)
            float4 r1 = rp[4 * c + 1];
            float4 r2 = rp[4 * c + 2];
            float4 r3 = rp[4 * c + 3];
            o0 = fmaf(r0.x, wc[16*c+ 0], o0); o0 = fmaf(r0.y, wc[16*c+ 1], o0);
            o0 = fmaf(r0.z, wc[16*c+ 2], o0); o0 = fmaf(r0.w, wc[16*c+ 3], o0);
            o1 = fmaf(r1.x, wc[16*c+ 4], o1); o1 = fmaf(r1.y, wc[16*c+ 5], o1);
            o1 = fmaf(r1.z, wc[16*c+ 6], o1); o1 = fmaf(r1.w, wc[16*c+ 7], o1);
            o2 = fmaf(r2.x, wc[16*c+ 8], o2); o2 = fmaf(r2.y, wc[16*c+ 9], o2);
            o2 = fmaf(r2.z, wc[16*c+10], o2); o2 = fmaf(r2.w, wc[16*c+11], o2);
            o3 = fmaf(r3.x, wc[16*c+12], o3); o3 = fmaf(r3.y, wc[16*c+13], o3);
            o3 = fmaf(r3.z, wc[16*c+14], o3); o3 = fmaf(r3.w, wc[16*c+15], o3);
        }
        tn1[(size_t)node * 64 + lane] = __float2half((o0 + o1) + (o2 + o3));
    }
}

// ---------------------------------------------------------------------------
// Layer 2+3a aggregate: pure gather+sum of tn1 (lane = feature, 128B/edge
// fully coalesced) + all-register epilogue: bias+ReLU+dinv, dot W3, butterfly
// reduce -> t3[n].  NO LDS objects at all.
__global__ __launch_bounds__(256) void k_layer2agg(const int* __restrict__ rowptr,
                                                   const int* __restrict__ ssrc,
                                                   const __half* __restrict__ tn1,
                                                   const float* __restrict__ dinv,
                                                   const float* __restrict__ b2,
                                                   const float* __restrict__ W3,
                                                   float* __restrict__ t3) {
    int node = blockIdx.x * 4 + (threadIdx.x >> 6);   // NN = 4*25000 exact
    int lane = threadIdx.x & 63;
    int start = rowptr[node], end = rowptr[node + 1];
    float acc = __half2float(tn1[(size_t)node * 64 + lane]);  // self loop
    int i = start;
    for (; i + 4 <= end; i += 4) {
        int s0 = ssrc[i], s1 = ssrc[i + 1], s2 = ssrc[i + 2], s3 = ssrc[i + 3];
        float a0 = __half2float(tn1[(size_t)s0 * 64 + lane]);
        float a1 = __half2float(tn1[(size_t)s1 * 64 + lane]);
        float a2 = __half2float(tn1[(size_t)s2 * 64 + lane]);
        float a3 = __half2float(tn1[(size_t)s3 * 64 + lane]);
        acc += a0 + a1 + a2 + a3;
    }
    for (; i < end; ++i) acc += __half2float(tn1[(size_t)ssrc[i] * 64 + lane]);
    float di = dinv[node];
    float v = fmaf(di, acc, b2[lane]);
    float r = di * fmaxf(v, 0.f) * W3[lane];   // hn2 element * W3, then reduce
#pragma unroll
    for (int m = 1; m < 64; m <<= 1) r += __shfl_xor(r, m, 64);
    if (lane == 0) t3[node] = r;
}

// Scalar last layer: out[n] = dinv[n]*(t3[n] + sum t3[src]) + b3
__global__ void k_aggregate3(const int* __restrict__ rowptr, const int* __restrict__ ssrc,
                             const float* __restrict__ t3, const float* __restrict__ dinv,
                             const float* __restrict__ b3, float* __restrict__ out) {
    int n = blockIdx.x * blockDim.x + threadIdx.x;
    if (n >= NN) return;
    int s = rowptr[n], e = rowptr[n + 1];
    float acc = t3[n];
    int i = s;
    for (; i + 4 <= e; i += 4)
        acc += t3[ssrc[i]] + t3[ssrc[i + 1]] + t3[ssrc[i + 2]] + t3[ssrc[i + 3]];
    for (; i < e; ++i) acc += t3[ssrc[i]];
    out[n] = dinv[n] * acc + b3[0];
}

// ---------------------------------------------------------------------------
extern "C" void kernel_launch(void* const* d_in, const int* in_sizes, int n_in,
                              void* d_out, int out_size, void* d_ws, size_t ws_size,
                              hipStream_t stream) {
    const float* x  = (const float*)d_in[0];
    const void*  ei = d_in[1];
    const float* W1 = (const float*)d_in[2];
    const float* b1 = (const float*)d_in[3];
    const float* W2 = (const float*)d_in[4];
    const float* b2 = (const float*)d_in[5];
    const float* W3 = (const float*)d_in[6];
    const float* b3 = (const float*)d_in[7];
    float* out = (float*)d_out;

    char* ws = (char*)d_ws;
    size_t off_b = 0;
    auto take = [&](size_t bytes) -> char* {
        char* p = ws + off_b;
        off_b = (off_b + bytes + 255) & ~(size_t)255;
        return p;
    };
    float*    dinv   = (float*)take((size_t)NN * 4);
    int*      flag   = (int*)take(4);
    int*      bsum   = (int*)take(128 * 4);
    int*      rowptr = (int*)take((size_t)(NN + 1) * 4);
    int*      hist   = (int*)take((size_t)NSC * 4);
    int*      histS  = (int*)take((size_t)NSC * 4);
    unsigned* packed = (unsigned*)take((size_t)NE * 4);
    int*      ssrc   = (int*)take((size_t)NE * 4);
    float2*   xn     = (float2*)take((size_t)NN * 8);
    float*    hn1    = (float*)take((size_t)NN * 64 * 4);
    __half*   tn1    = (__half*)take((size_t)NN * 64 * 2);
    float*    t3     = (float*)take((size_t)NN * 4);

    // --- edge dtype detect ---
    hipMemsetAsync(flag, 0, 4, stream);
    k_detect<<<256, 256, 0, stream>>>((const unsigned int*)ei, flag);

    // --- atomic-free radix partition by dst (coarse buckets of 256 nodes) ---
    k_hist<<<B_P, 256, 0, stream>>>(ei, flag, hist);
    k_gscan1<<<NBLK_H, 256, 0, stream>>>(hist, histS, bsum, NSC);
    k_gscan2<<<1, 128, 0, stream>>>(bsum, NBLK_H);
    k_gscan3<<<(NSC + 255) / 256, 256, 0, stream>>>(histS, bsum, NSC);
    k_part<<<B_P, 256, 0, stream>>>(ei, flag, histS, packed);

    // --- fused per-bucket: count + scan -> rowptr/dinv/xn + place ssrc ---
    k_bucket<<<K_B, 256, 0, stream>>>(histS, packed, x, rowptr, dinv, xn, ssrc);

    const int nblk_agg = (NN + 3) / 4;  // 4 waves (nodes) per block

    // --- layer 1 (lane-parallel 2-wide aggregate + transform, fp32 out) ---
    k_layer1<<<nblk_agg, 256, 0, stream>>>(rowptr, ssrc, xn, dinv, W1, b1, hn1);

    // --- dense 64x64 transform (register-W2, zero LDS) ---
    k_gemmW2<<<GW2_GRID, 256, 0, stream>>>(hn1, W2, tn1);

    // --- layer 2 aggregate + epilogue + W3 dot ---
    k_layer2agg<<<nblk_agg, 256, 0, stream>>>(rowptr, ssrc, tn1, dinv, b2, W3, t3);

    // --- layer 3b (scalar aggregate) ---
    k_aggregate3<<<(NN + 255) / 256, 256, 0, stream>>>(rowptr, ssrc, t3, dinv, b3, out);
}

// Round 13
// 193.390 us; speedup vs baseline: 1.1380x; 1.1380x over previous
//
#include <hip/hip_runtime.h>
#include <hip/hip_fp16.h>

#define NN 100000
#define NE 1600000

// Radix partition params: buckets of 256 nodes
#define K_B 391                          // ceil(NN/256) buckets
#define B_P 256                          // partition blocks
#define CH  ((NE + B_P - 1) / B_P)       // 6250 edges per partition block
#define NSC (K_B * B_P)                  // histogram table size (100096)
#define NBLK_H ((NSC + 1023) / 1024)     // 98 blocks for hist scan

// ---------------------------------------------------------------------------
// edge_index dtype detection: if int64 (values < 2^31), odd 32-bit words are 0.
__global__ void k_detect(const unsigned int* w, int* flag) {
    int i = blockIdx.x * blockDim.x + threadIdx.x;
    if (i < 65536 && w[2 * i + 1] != 0u) *flag = 1;
}

__device__ __forceinline__ void load_edge(const void* ei, int is32, int e,
                                          int& s, int& d) {
    if (is32) {
        const int* p = (const int*)ei;
        s = p[e]; d = p[NE + e];
    } else {
        const long long* p = (const long long*)ei;
        s = (int)p[e]; d = (int)p[NE + e];
    }
}

// ---------------------------------------------------------------------------
// P1: per-block histogram of dst>>8 over this block's edge chunk
__global__ __launch_bounds__(256) void k_hist(const void* ei, const int* __restrict__ flag,
                                              int* __restrict__ hist) {
    __shared__ int h[K_B];
    for (int i = threadIdx.x; i < K_B; i += 256) h[i] = 0;
    __syncthreads();
    int b = blockIdx.x;
    int is32 = *flag;
    int e0 = b * CH, e1 = min(e0 + CH, NE);
    for (int e = e0 + threadIdx.x; e < e1; e += 256) {
        int d = is32 ? ((const int*)ei)[NE + e] : (int)((const long long*)ei)[NE + e];
        atomicAdd(&h[d >> 8], 1);
    }
    __syncthreads();
    for (int i = threadIdx.x; i < K_B; i += 256) hist[i * B_P + b] = h[i];
}

// ---------------------------------------------------------------------------
// Generalized hierarchical exclusive scan (3 kernels), n <= 128*1024
__global__ __launch_bounds__(256) void k_gscan1(const int* __restrict__ in,
                                                int* __restrict__ ex,
                                                int* __restrict__ bsum, int n) {
    __shared__ int lds[256];
    int b = blockIdx.x, t = threadIdx.x;
    int base = b * 1024 + t * 4;
    int v[4];
#pragma unroll
    for (int k = 0; k < 4; ++k) { int i = base + k; v[k] = (i < n) ? in[i] : 0; }
    int s = v[0] + v[1] + v[2] + v[3];
    lds[t] = s;
    __syncthreads();
    for (int off = 1; off < 256; off <<= 1) {
        int tmp = (t >= off) ? lds[t - off] : 0;
        __syncthreads();
        lds[t] += tmp;
        __syncthreads();
    }
    int run = lds[t] - s;
#pragma unroll
    for (int k = 0; k < 4; ++k) {
        int i = base + k;
        if (i < n) ex[i] = run;
        run += v[k];
    }
    if (t == 255) bsum[b] = lds[255];
}

__global__ __launch_bounds__(128) void k_gscan2(int* bsum, int nblk) {
    __shared__ int lds[128];
    int t = threadIdx.x;
    int v = (t < nblk) ? bsum[t] : 0;
    lds[t] = v;
    __syncthreads();
    for (int off = 1; off < 128; off <<= 1) {
        int tmp = (t >= off) ? lds[t - off] : 0;
        __syncthreads();
        lds[t] += tmp;
        __syncthreads();
    }
    if (t < nblk) bsum[t] = lds[t] - v;  // exclusive
}

__global__ void k_gscan3(int* __restrict__ ex, const int* __restrict__ bsum, int n) {
    int i = blockIdx.x * blockDim.x + threadIdx.x;
    if (i < n) ex[i] += bsum[i >> 10];
}

// ---------------------------------------------------------------------------
// P3: partition edges into per-(block,bucket) contiguous runs (LDS cursors only)
__global__ __launch_bounds__(256) void k_part(const void* ei, const int* __restrict__ flag,
                                              const int* __restrict__ off,
                                              unsigned* __restrict__ packed) {
    __shared__ int cur[K_B];
    int b = blockIdx.x;
    for (int i = threadIdx.x; i < K_B; i += 256) cur[i] = off[i * B_P + b];
    __syncthreads();
    int is32 = *flag;
    int e0 = b * CH, e1 = min(e0 + CH, NE);
    for (int e = e0 + threadIdx.x; e < e1; e += 256) {
        int s, d;
        load_edge(ei, is32, e, s, d);
        int k = d >> 8;
        int pos = atomicAdd(&cur[k], 1);
        packed[pos] = ((unsigned)s << 8) | (unsigned)(d & 255);
    }
}

// ---------------------------------------------------------------------------
// P4 fused per-bucket: count -> local scan -> rowptr/dinv/xn -> place ssrc.
__global__ __launch_bounds__(256) void k_bucket(const int* __restrict__ off,
                                                const unsigned* __restrict__ packed,
                                                const float* __restrict__ x,
                                                int* __restrict__ rowptr,
                                                float* __restrict__ dinv,
                                                float2* __restrict__ xn,
                                                int* __restrict__ ssrc) {
    __shared__ int cnt[256];
    __shared__ int excl[256];
    int k = blockIdx.x, t = threadIdx.x;
    cnt[t] = 0;
    __syncthreads();
    int g0 = off[k * B_P];
    int g1 = (k == K_B - 1) ? NE : off[(k + 1) * B_P];
    for (int i = g0 + t; i < g1; i += 256)
        atomicAdd(&cnt[packed[i] & 255u], 1);
    __syncthreads();
    int v = cnt[t];
    excl[t] = v;
    __syncthreads();
    for (int o = 1; o < 256; o <<= 1) {
        int tmp = (t >= o) ? excl[t - o] : 0;
        __syncthreads();
        excl[t] += tmp;
        __syncthreads();
    }
    int rb = g0 + excl[t] - v;  // rowptr[n]: bucket start + local exclusive prefix
    int n = (k << 8) + t;
    if (n < NN) {
        rowptr[n] = rb;
        float di = rsqrtf((float)(v + 1));  // +1 self-loop
        dinv[n] = di;
        float2 xv = ((const float2*)x)[n];
        xn[n] = make_float2(xv.x * di, xv.y * di);
    }
    if (k == K_B - 1 && t == 0) rowptr[NN] = NE;
    __syncthreads();
    excl[t] = rb;   // reuse as row base for placement
    cnt[t] = 0;
    __syncthreads();
    for (int i = g0 + t; i < g1; i += 256) {
        unsigned pk = packed[i];
        int dl = pk & 255u;
        int r = atomicAdd(&cnt[dl], 1);
        ssrc[excl[dl] + r] = (int)(pk >> 8);
    }
}

// ---------------------------------------------------------------------------
// Layer 1 fused: lane-parallel agg of xn (2-wide) + 2->64 transform + bias +
// ReLU + next-layer dinv scale.  hn1[n][j] = fp16( dinv[n]*relu(...) )
__global__ __launch_bounds__(256) void k_layer1(const int* __restrict__ rowptr,
                                                const int* __restrict__ ssrc,
                                                const float2* __restrict__ xn,
                                                const float* __restrict__ dinv,
                                                const float* __restrict__ W1,
                                                const float* __restrict__ b1,
                                                __half* __restrict__ hn1) {
    int node = blockIdx.x * 4 + (threadIdx.x >> 6);
    if (node >= NN) return;
    int lane = threadIdx.x & 63;
    int s0 = rowptr[node], e0 = rowptr[node + 1];
    float ax = 0.f, ay = 0.f;
    for (int i = s0 + lane; i < e0; i += 64) {
        float2 v = xn[ssrc[i]];
        ax += v.x; ay += v.y;
    }
#pragma unroll
    for (int m = 1; m < 64; m <<= 1) {
        ax += __shfl_xor(ax, m, 64);
        ay += __shfl_xor(ay, m, 64);
    }
    float2 a = xn[node];  // self loop
    ax += a.x; ay += a.y;
    float di = dinv[node];
    ax *= di; ay *= di;
    float v = fmaf(ax, W1[lane], fmaf(ay, W1[64 + lane], b1[lane]));
    hn1[(size_t)node * 64 + lane] = __float2half(di * fmaxf(v, 0.f));
}

// ---------------------------------------------------------------------------
// Layer 2+3a fused (r11 structure, optimized epilogue): per-lane fp16 gather
// (lane = feature, 128B/edge coalesced, unroll 8) then 64x64 GEMM from LDS
// with TRANSPOSED+PADDED weights: WsT[j][k]=W2[k][j], row stride 68 floats
// (17 float4 == 1 mod 8 -> conflict-free ds_read_b128 across lanes).
// Epilogue: 16 b128 WsT reads + 16 b128 gs broadcasts per node (was 128
// scalar ds_reads). gs publish is all-lane write + same-wave reads
// (wave-synchronous, in-order LDS — proven pattern from r7/r8).
__global__ __launch_bounds__(256) void k_layer2(const int* __restrict__ rowptr,
                                                const int* __restrict__ ssrc,
                                                const __half* __restrict__ hn1,
                                                const float* __restrict__ dinv,
                                                const float* __restrict__ W2,
                                                const float* __restrict__ b2,
                                                const float* __restrict__ W3,
                                                float* __restrict__ t3) {
    __shared__ float WsT[64][68];   // transposed W2, padded row stride
    __shared__ float gs[4][64];
    for (int i = threadIdx.x; i < 64 * 64; i += 256) {
        int k = i >> 6, j = i & 63;
        WsT[j][k] = W2[i];          // W2 row-major [k][j]
    }
    __syncthreads();
    int node = blockIdx.x * 4 + (threadIdx.x >> 6);   // NN = 4*25000 exact
    int w = threadIdx.x >> 6, lane = threadIdx.x & 63;
    int start = rowptr[node], end = rowptr[node + 1];
    float acc = __half2float(hn1[(size_t)node * 64 + lane]);  // self loop
    int i = start;
    for (; i + 8 <= end; i += 8) {
        int s0 = ssrc[i + 0], s1 = ssrc[i + 1], s2 = ssrc[i + 2], s3 = ssrc[i + 3];
        int s4 = ssrc[i + 4], s5 = ssrc[i + 5], s6 = ssrc[i + 6], s7 = ssrc[i + 7];
        float a0 = __half2float(hn1[(size_t)s0 * 64 + lane]);
        float a1 = __half2float(hn1[(size_t)s1 * 64 + lane]);
        float a2 = __half2float(hn1[(size_t)s2 * 64 + lane]);
        float a3 = __half2float(hn1[(size_t)s3 * 64 + lane]);
        float a4 = __half2float(hn1[(size_t)s4 * 64 + lane]);
        float a5 = __half2float(hn1[(size_t)s5 * 64 + lane]);
        float a6 = __half2float(hn1[(size_t)s6 * 64 + lane]);
        float a7 = __half2float(hn1[(size_t)s7 * 64 + lane]);
        acc += ((a0 + a1) + (a2 + a3)) + ((a4 + a5) + (a6 + a7));
    }
    for (; i < end; ++i) acc += __half2float(hn1[(size_t)ssrc[i] * 64 + lane]);
    gs[w][lane] = acc;              // all-lane publish, same-wave consume
    float o = 0.f;
    const float4* gp = (const float4*)gs[w];
#pragma unroll
    for (int c = 0; c < 16; ++c) {
        float4 g4 = gp[c];                               // LDS broadcast
        float4 w4 = *(const float4*)&WsT[lane][4 * c];   // conflict-free b128
        o = fmaf(g4.x, w4.x, o);
        o = fmaf(g4.y, w4.y, o);
        o = fmaf(g4.z, w4.z, o);
        o = fmaf(g4.w, w4.w, o);
    }
    float di = dinv[node];
    float v = fmaf(di, o, b2[lane]);
    float r = di * fmaxf(v, 0.f) * W3[lane];   // hn2 element * W3, then reduce
#pragma unroll
    for (int m = 1; m < 64; m <<= 1) r += __shfl_xor(r, m, 64);
    if (lane == 0) t3[node] = r;
}

// Scalar last layer: out[n] = dinv[n]*(t3[n] + sum t3[src]) + b3
__global__ void k_aggregate3(const int* __restrict__ rowptr, const int* __restrict__ ssrc,
                             const float* __restrict__ t3, const float* __restrict__ dinv,
                             const float* __restrict__ b3, float* __restrict__ out) {
    int n = blockIdx.x * blockDim.x + threadIdx.x;
    if (n >= NN) return;
    int s = rowptr[n], e = rowptr[n + 1];
    float acc = t3[n];
    int i = s;
    for (; i + 4 <= e; i += 4)
        acc += t3[ssrc[i]] + t3[ssrc[i + 1]] + t3[ssrc[i + 2]] + t3[ssrc[i + 3]];
    for (; i < e; ++i) acc += t3[ssrc[i]];
    out[n] = dinv[n] * acc + b3[0];
}

// ---------------------------------------------------------------------------
extern "C" void kernel_launch(void* const* d_in, const int* in_sizes, int n_in,
                              void* d_out, int out_size, void* d_ws, size_t ws_size,
                              hipStream_t stream) {
    const float* x  = (const float*)d_in[0];
    const void*  ei = d_in[1];
    const float* W1 = (const float*)d_in[2];
    const float* b1 = (const float*)d_in[3];
    const float* W2 = (const float*)d_in[4];
    const float* b2 = (const float*)d_in[5];
    const float* W3 = (const float*)d_in[6];
    const float* b3 = (const float*)d_in[7];
    float* out = (float*)d_out;

    char* ws = (char*)d_ws;
    size_t off_b = 0;
    auto take = [&](size_t bytes) -> char* {
        char* p = ws + off_b;
        off_b = (off_b + bytes + 255) & ~(size_t)255;
        return p;
    };
    float*    dinv   = (float*)take((size_t)NN * 4);
    int*      flag   = (int*)take(4);
    int*      bsum   = (int*)take(128 * 4);
    int*      rowptr = (int*)take((size_t)(NN + 1) * 4);
    int*      hist   = (int*)take((size_t)NSC * 4);
    int*      histS  = (int*)take((size_t)NSC * 4);
    unsigned* packed = (unsigned*)take((size_t)NE * 4);
    int*      ssrc   = (int*)take((size_t)NE * 4);
    float2*   xn     = (float2*)take((size_t)NN * 8);
    __half*   hn1    = (__half*)take((size_t)NN * 64 * 2);
    float*    t3     = (float*)take((size_t)NN * 4);

    // --- edge dtype detect ---
    hipMemsetAsync(flag, 0, 4, stream);
    k_detect<<<256, 256, 0, stream>>>((const unsigned int*)ei, flag);

    // --- atomic-free radix partition by dst (coarse buckets of 256 nodes) ---
    k_hist<<<B_P, 256, 0, stream>>>(ei, flag, hist);
    k_gscan1<<<NBLK_H, 256, 0, stream>>>(hist, histS, bsum, NSC);
    k_gscan2<<<1, 128, 0, stream>>>(bsum, NBLK_H);
    k_gscan3<<<(NSC + 255) / 256, 256, 0, stream>>>(histS, bsum, NSC);
    k_part<<<B_P, 256, 0, stream>>>(ei, flag, histS, packed);

    // --- fused per-bucket: count + scan -> rowptr/dinv/xn + place ssrc ---
    k_bucket<<<K_B, 256, 0, stream>>>(histS, packed, x, rowptr, dinv, xn, ssrc);

    const int nblk_agg = (NN + 3) / 4;  // 4 waves (nodes) per block

    // --- layer 1 (lane-parallel 2-wide aggregate + transform, fp16 out) ---
    k_layer1<<<nblk_agg, 256, 0, stream>>>(rowptr, ssrc, xn, dinv, W1, b1, hn1);

    // --- layer 2 + 3a (fused gather + b128-LDS GEMM + W3 dot) ---
    k_layer2<<<nblk_agg, 256, 0, stream>>>(rowptr, ssrc, hn1, dinv, W2, b2, W3, t3);

    // --- layer 3b (scalar aggregate) ---
    k_aggregate3<<<(NN + 255) / 256, 256, 0, stream>>>(rowptr, ssrc, t3, dinv, b3, out);
}

// Round 14
// 183.766 us; speedup vs baseline: 1.1976x; 1.0524x over previous
//
#include <hip/hip_runtime.h>
#include <hip/hip_fp16.h>

#define NN 100000
#define NE 1600000

// Radix partition params: buckets of 256 nodes
#define K_B 391                          // ceil(NN/256) buckets
#define B_P 256                          // partition blocks
#define CH  ((NE + B_P - 1) / B_P)       // 6250 edges per partition block
#define NSC (K_B * B_P)                  // histogram table size (100096)
#define NBLK_H ((NSC + 1023) / 1024)     // 98 blocks for hist scan

// ---------------------------------------------------------------------------
// edge_index dtype detection: if int64 (values < 2^31), odd 32-bit words are 0.
__global__ void k_detect(const unsigned int* w, int* flag) {
    int i = blockIdx.x * blockDim.x + threadIdx.x;
    if (i < 65536 && w[2 * i + 1] != 0u) *flag = 1;
}

__device__ __forceinline__ void load_edge(const void* ei, int is32, int e,
                                          int& s, int& d) {
    if (is32) {
        const int* p = (const int*)ei;
        s = p[e]; d = p[NE + e];
    } else {
        const long long* p = (const long long*)ei;
        s = (int)p[e]; d = (int)p[NE + e];
    }
}

// ---------------------------------------------------------------------------
// P1: per-block histogram of dst>>8 over this block's edge chunk
__global__ __launch_bounds__(256) void k_hist(const void* ei, const int* __restrict__ flag,
                                              int* __restrict__ hist) {
    __shared__ int h[K_B];
    for (int i = threadIdx.x; i < K_B; i += 256) h[i] = 0;
    __syncthreads();
    int b = blockIdx.x;
    int is32 = *flag;
    int e0 = b * CH, e1 = min(e0 + CH, NE);
    for (int e = e0 + threadIdx.x; e < e1; e += 256) {
        int d = is32 ? ((const int*)ei)[NE + e] : (int)((const long long*)ei)[NE + e];
        atomicAdd(&h[d >> 8], 1);
    }
    __syncthreads();
    for (int i = threadIdx.x; i < K_B; i += 256) hist[i * B_P + b] = h[i];
}

// ---------------------------------------------------------------------------
// Generalized hierarchical exclusive scan (3 kernels), n <= 128*1024
__global__ __launch_bounds__(256) void k_gscan1(const int* __restrict__ in,
                                                int* __restrict__ ex,
                                                int* __restrict__ bsum, int n) {
    __shared__ int lds[256];
    int b = blockIdx.x, t = threadIdx.x;
    int base = b * 1024 + t * 4;
    int v[4];
#pragma unroll
    for (int k = 0; k < 4; ++k) { int i = base + k; v[k] = (i < n) ? in[i] : 0; }
    int s = v[0] + v[1] + v[2] + v[3];
    lds[t] = s;
    __syncthreads();
    for (int off = 1; off < 256; off <<= 1) {
        int tmp = (t >= off) ? lds[t - off] : 0;
        __syncthreads();
        lds[t] += tmp;
        __syncthreads();
    }
    int run = lds[t] - s;
#pragma unroll
    for (int k = 0; k < 4; ++k) {
        int i = base + k;
        if (i < n) ex[i] = run;
        run += v[k];
    }
    if (t == 255) bsum[b] = lds[255];
}

__global__ __launch_bounds__(128) void k_gscan2(int* bsum, int nblk) {
    __shared__ int lds[128];
    int t = threadIdx.x;
    int v = (t < nblk) ? bsum[t] : 0;
    lds[t] = v;
    __syncthreads();
    for (int off = 1; off < 128; off <<= 1) {
        int tmp = (t >= off) ? lds[t - off] : 0;
        __syncthreads();
        lds[t] += tmp;
        __syncthreads();
    }
    if (t < nblk) bsum[t] = lds[t] - v;  // exclusive
}

__global__ void k_gscan3(int* __restrict__ ex, const int* __restrict__ bsum, int n) {
    int i = blockIdx.x * blockDim.x + threadIdx.x;
    if (i < n) ex[i] += bsum[i >> 10];
}

// ---------------------------------------------------------------------------
// P3: partition edges into per-(block,bucket) contiguous runs (LDS cursors only)
__global__ __launch_bounds__(256) void k_part(const void* ei, const int* __restrict__ flag,
                                              const int* __restrict__ off,
                                              unsigned* __restrict__ packed) {
    __shared__ int cur[K_B];
    int b = blockIdx.x;
    for (int i = threadIdx.x; i < K_B; i += 256) cur[i] = off[i * B_P + b];
    __syncthreads();
    int is32 = *flag;
    int e0 = b * CH, e1 = min(e0 + CH, NE);
    for (int e = e0 + threadIdx.x; e < e1; e += 256) {
        int s, d;
        load_edge(ei, is32, e, s, d);
        int k = d >> 8;
        int pos = atomicAdd(&cur[k], 1);
        packed[pos] = ((unsigned)s << 8) | (unsigned)(d & 255);
    }
}

// ---------------------------------------------------------------------------
// P4 fused per-bucket: count -> local scan -> rowptr/dinv/xn -> place ssrc.
__global__ __launch_bounds__(256) void k_bucket(const int* __restrict__ off,
                                                const unsigned* __restrict__ packed,
                                                const float* __restrict__ x,
                                                int* __restrict__ rowptr,
                                                float* __restrict__ dinv,
                                                float2* __restrict__ xn,
                                                int* __restrict__ ssrc) {
    __shared__ int cnt[256];
    __shared__ int excl[256];
    int k = blockIdx.x, t = threadIdx.x;
    cnt[t] = 0;
    __syncthreads();
    int g0 = off[k * B_P];
    int g1 = (k == K_B - 1) ? NE : off[(k + 1) * B_P];
    for (int i = g0 + t; i < g1; i += 256)
        atomicAdd(&cnt[packed[i] & 255u], 1);
    __syncthreads();
    int v = cnt[t];
    excl[t] = v;
    __syncthreads();
    for (int o = 1; o < 256; o <<= 1) {
        int tmp = (t >= o) ? excl[t - o] : 0;
        __syncthreads();
        excl[t] += tmp;
        __syncthreads();
    }
    int rb = g0 + excl[t] - v;  // rowptr[n]: bucket start + local exclusive prefix
    int n = (k << 8) + t;
    if (n < NN) {
        rowptr[n] = rb;
        float di = rsqrtf((float)(v + 1));  // +1 self-loop
        dinv[n] = di;
        float2 xv = ((const float2*)x)[n];
        xn[n] = make_float2(xv.x * di, xv.y * di);
    }
    if (k == K_B - 1 && t == 0) rowptr[NN] = NE;
    __syncthreads();
    excl[t] = rb;   // reuse as row base for placement
    cnt[t] = 0;
    __syncthreads();
    for (int i = g0 + t; i < g1; i += 256) {
        unsigned pk = packed[i];
        int dl = pk & 255u;
        int r = atomicAdd(&cnt[dl], 1);
        ssrc[excl[dl] + r] = (int)(pk >> 8);
    }
}

// ---------------------------------------------------------------------------
// Layer 1 fused: lane-parallel agg of xn (2-wide) + 2->64 transform + bias +
// ReLU + next-layer dinv scale.  hn1[n][j] = fp32( dinv[n]*relu(...) )
__global__ __launch_bounds__(256) void k_layer1(const int* __restrict__ rowptr,
                                                const int* __restrict__ ssrc,
                                                const float2* __restrict__ xn,
                                                const float* __restrict__ dinv,
                                                const float* __restrict__ W1,
                                                const float* __restrict__ b1,
                                                float* __restrict__ hn1) {
    int node = blockIdx.x * 4 + (threadIdx.x >> 6);
    if (node >= NN) return;
    int lane = threadIdx.x & 63;
    int s0 = rowptr[node], e0 = rowptr[node + 1];
    float ax = 0.f, ay = 0.f;
    for (int i = s0 + lane; i < e0; i += 64) {
        float2 v = xn[ssrc[i]];
        ax += v.x; ay += v.y;
    }
#pragma unroll
    for (int m = 1; m < 64; m <<= 1) {
        ax += __shfl_xor(ax, m, 64);
        ay += __shfl_xor(ay, m, 64);
    }
    float2 a = xn[node];  // self loop
    ax += a.x; ay += a.y;
    float di = dinv[node];
    ax *= di; ay *= di;
    float v = fmaf(ax, W1[lane], fmaf(ay, W1[64 + lane], b1[lane]));
    hn1[(size_t)node * 64 + lane] = di * fmaxf(v, 0.f);
}

// ---------------------------------------------------------------------------
// Dense transform tn1 = hn1 @ W2 (fp16 out), LANE = NODE mapping:
// each thread owns one node's row (float4 loads, lanes' lines L1-combined)
// and 64 fp32 accumulators; W2 is read ROW-wise at wave-uniform addresses ->
// compiler scalarizes to s_load, inner loop is v_fma with SGPR operand.
// No LDS, no cross-lane — the per-node matvec runs entirely on the VALU
// (the LDS pipe was the measured bottleneck of every fused variant).
__global__ __launch_bounds__(256) void k_gemmW2(const float* __restrict__ hn1,
                                                const float* __restrict__ W2,
                                                __half* __restrict__ tn1) {
    int node = blockIdx.x * 256 + threadIdx.x;
    if (node >= NN) return;
    const float4* hp = (const float4*)(hn1 + (size_t)node * 64);
    float acc[64];
#pragma unroll
    for (int j = 0; j < 64; ++j) acc[j] = 0.f;
    for (int kc = 0; kc < 16; ++kc) {            // NOT unrolled: keep I$ small
        float4 h4 = hp[kc];
        const float* wr0 = W2 + (4 * kc + 0) * 64;   // wave-uniform rows
        const float* wr1 = W2 + (4 * kc + 1) * 64;
        const float* wr2 = W2 + (4 * kc + 2) * 64;
        const float* wr3 = W2 + (4 * kc + 3) * 64;
#pragma unroll
        for (int j = 0; j < 64; ++j) {
            float a = acc[j];
            a = fmaf(h4.x, wr0[j], a);
            a = fmaf(h4.y, wr1[j], a);
            a = fmaf(h4.z, wr2[j], a);
            a = fmaf(h4.w, wr3[j], a);
            acc[j] = a;
        }
    }
    __half2* op = (__half2*)(tn1 + (size_t)node * 64);
#pragma unroll
    for (int jp = 0; jp < 32; ++jp)
        op[jp] = __floats2half2_rn(acc[2 * jp], acc[2 * jp + 1]);
}

// ---------------------------------------------------------------------------
// Layer 2+3a aggregate: pure gather+sum of tn1 (lane = feature, 128B/edge
// fully coalesced) + all-register epilogue: bias+ReLU+dinv, dot W3, butterfly
// reduce -> t3[n].  NO LDS objects at all.
__global__ __launch_bounds__(256) void k_layer2agg(const int* __restrict__ rowptr,
                                                   const int* __restrict__ ssrc,
                                                   const __half* __restrict__ tn1,
                                                   const float* __restrict__ dinv,
                                                   const float* __restrict__ b2,
                                                   const float* __restrict__ W3,
                                                   float* __restrict__ t3) {
    int node = blockIdx.x * 4 + (threadIdx.x >> 6);   // NN = 4*25000 exact
    int lane = threadIdx.x & 63;
    int start = rowptr[node], end = rowptr[node + 1];
    float acc = __half2float(tn1[(size_t)node * 64 + lane]);  // self loop
    int i = start;
    for (; i + 4 <= end; i += 4) {
        int s0 = ssrc[i], s1 = ssrc[i + 1], s2 = ssrc[i + 2], s3 = ssrc[i + 3];
        float a0 = __half2float(tn1[(size_t)s0 * 64 + lane]);
        float a1 = __half2float(tn1[(size_t)s1 * 64 + lane]);
        float a2 = __half2float(tn1[(size_t)s2 * 64 + lane]);
        float a3 = __half2float(tn1[(size_t)s3 * 64 + lane]);
        acc += a0 + a1 + a2 + a3;
    }
    for (; i < end; ++i) acc += __half2float(tn1[(size_t)ssrc[i] * 64 + lane]);
    float di = dinv[node];
    float v = fmaf(di, acc, b2[lane]);
    float r = di * fmaxf(v, 0.f) * W3[lane];   // hn2 element * W3, then reduce
#pragma unroll
    for (int m = 1; m < 64; m <<= 1) r += __shfl_xor(r, m, 64);
    if (lane == 0) t3[node] = r;
}

// Scalar last layer: out[n] = dinv[n]*(t3[n] + sum t3[src]) + b3
__global__ void k_aggregate3(const int* __restrict__ rowptr, const int* __restrict__ ssrc,
                             const float* __restrict__ t3, const float* __restrict__ dinv,
                             const float* __restrict__ b3, float* __restrict__ out) {
    int n = blockIdx.x * blockDim.x + threadIdx.x;
    if (n >= NN) return;
    int s = rowptr[n], e = rowptr[n + 1];
    float acc = t3[n];
    int i = s;
    for (; i + 4 <= e; i += 4)
        acc += t3[ssrc[i]] + t3[ssrc[i + 1]] + t3[ssrc[i + 2]] + t3[ssrc[i + 3]];
    for (; i < e; ++i) acc += t3[ssrc[i]];
    out[n] = dinv[n] * acc + b3[0];
}

// ---------------------------------------------------------------------------
extern "C" void kernel_launch(void* const* d_in, const int* in_sizes, int n_in,
                              void* d_out, int out_size, void* d_ws, size_t ws_size,
                              hipStream_t stream) {
    const float* x  = (const float*)d_in[0];
    const void*  ei = d_in[1];
    const float* W1 = (const float*)d_in[2];
    const float* b1 = (const float*)d_in[3];
    const float* W2 = (const float*)d_in[4];
    const float* b2 = (const float*)d_in[5];
    const float* W3 = (const float*)d_in[6];
    const float* b3 = (const float*)d_in[7];
    float* out = (float*)d_out;

    char* ws = (char*)d_ws;
    size_t off_b = 0;
    auto take = [&](size_t bytes) -> char* {
        char* p = ws + off_b;
        off_b = (off_b + bytes + 255) & ~(size_t)255;
        return p;
    };
    float*    dinv   = (float*)take((size_t)NN * 4);
    int*      flag   = (int*)take(4);
    int*      bsum   = (int*)take(128 * 4);
    int*      rowptr = (int*)take((size_t)(NN + 1) * 4);
    int*      hist   = (int*)take((size_t)NSC * 4);
    int*      histS  = (int*)take((size_t)NSC * 4);
    unsigned* packed = (unsigned*)take((size_t)NE * 4);
    int*      ssrc   = (int*)take((size_t)NE * 4);
    float2*   xn     = (float2*)take((size_t)NN * 8);
    float*    hn1    = (float*)take((size_t)NN * 64 * 4);
    __half*   tn1    = (__half*)take((size_t)NN * 64 * 2);
    float*    t3     = (float*)take((size_t)NN * 4);

    // --- edge dtype detect ---
    hipMemsetAsync(flag, 0, 4, stream);
    k_detect<<<256, 256, 0, stream>>>((const unsigned int*)ei, flag);

    // --- atomic-free radix partition by dst (coarse buckets of 256 nodes) ---
    k_hist<<<B_P, 256, 0, stream>>>(ei, flag, hist);
    k_gscan1<<<NBLK_H, 256, 0, stream>>>(hist, histS, bsum, NSC);
    k_gscan2<<<1, 128, 0, stream>>>(bsum, NBLK_H);
    k_gscan3<<<(NSC + 255) / 256, 256, 0, stream>>>(histS, bsum, NSC);
    k_part<<<B_P, 256, 0, stream>>>(ei, flag, histS, packed);

    // --- fused per-bucket: count + scan -> rowptr/dinv/xn + place ssrc ---
    k_bucket<<<K_B, 256, 0, stream>>>(histS, packed, x, rowptr, dinv, xn, ssrc);

    const int nblk_agg = (NN + 3) / 4;  // 4 waves (nodes) per block

    // --- layer 1 (lane-parallel 2-wide aggregate + transform, fp32 out) ---
    k_layer1<<<nblk_agg, 256, 0, stream>>>(rowptr, ssrc, xn, dinv, W1, b1, hn1);

    // --- dense 64x64 transform (lane=node, VALU-only matvec) ---
    k_gemmW2<<<(NN + 255) / 256, 256, 0, stream>>>(hn1, W2, tn1);

    // --- layer 2 aggregate + epilogue + W3 dot ---
    k_layer2agg<<<nblk_agg, 256, 0, stream>>>(rowptr, ssrc, tn1, dinv, b2, W3, t3);

    // --- layer 3b (scalar aggregate) ---
    k_aggregate3<<<(NN + 255) / 256, 256, 0, stream>>>(rowptr, ssrc, t3, dinv, b3, out);
}

// Round 15
// 169.043 us; speedup vs baseline: 1.3019x; 1.0871x over previous
//
#include <hip/hip_runtime.h>
#include <hip/hip_fp16.h>

#define NN 100000
#define NE 1600000

// Radix partition params: buckets of 256 nodes
#define K_B 391                          // ceil(NN/256) buckets
#define B_P 256                          // partition blocks
#define CH  ((NE + B_P - 1) / B_P)       // 6250 edges per partition block
#define NSC (K_B * B_P)                  // histogram table size (100096)
#define NBLK_H ((NSC + 1023) / 1024)     // 98 blocks for hist scan

// ---------------------------------------------------------------------------
// edge_index dtype detection: if int64 (values < 2^31), odd 32-bit words are 0.
__global__ void k_detect(const unsigned int* w, int* flag) {
    int i = blockIdx.x * blockDim.x + threadIdx.x;
    if (i < 65536 && w[2 * i + 1] != 0u) *flag = 1;
}

__device__ __forceinline__ void load_edge(const void* ei, int is32, int e,
                                          int& s, int& d) {
    if (is32) {
        const int* p = (const int*)ei;
        s = p[e]; d = p[NE + e];
    } else {
        const long long* p = (const long long*)ei;
        s = (int)p[e]; d = (int)p[NE + e];
    }
}

// ---------------------------------------------------------------------------
// P1: per-block histogram of dst>>8 over this block's edge chunk
__global__ __launch_bounds__(256) void k_hist(const void* ei, const int* __restrict__ flag,
                                              int* __restrict__ hist) {
    __shared__ int h[K_B];
    for (int i = threadIdx.x; i < K_B; i += 256) h[i] = 0;
    __syncthreads();
    int b = blockIdx.x;
    int is32 = *flag;
    int e0 = b * CH, e1 = min(e0 + CH, NE);
    for (int e = e0 + threadIdx.x; e < e1; e += 256) {
        int d = is32 ? ((const int*)ei)[NE + e] : (int)((const long long*)ei)[NE + e];
        atomicAdd(&h[d >> 8], 1);
    }
    __syncthreads();
    for (int i = threadIdx.x; i < K_B; i += 256) hist[i * B_P + b] = h[i];
}

// ---------------------------------------------------------------------------
// Generalized hierarchical exclusive scan (3 kernels), n <= 128*1024
__global__ __launch_bounds__(256) void k_gscan1(const int* __restrict__ in,
                                                int* __restrict__ ex,
                                                int* __restrict__ bsum, int n) {
    __shared__ int lds[256];
    int b = blockIdx.x, t = threadIdx.x;
    int base = b * 1024 + t * 4;
    int v[4];
#pragma unroll
    for (int k = 0; k < 4; ++k) { int i = base + k; v[k] = (i < n) ? in[i] : 0; }
    int s = v[0] + v[1] + v[2] + v[3];
    lds[t] = s;
    __syncthreads();
    for (int off = 1; off < 256; off <<= 1) {
        int tmp = (t >= off) ? lds[t - off] : 0;
        __syncthreads();
        lds[t] += tmp;
        __syncthreads();
    }
    int run = lds[t] - s;
#pragma unroll
    for (int k = 0; k < 4; ++k) {
        int i = base + k;
        if (i < n) ex[i] = run;
        run += v[k];
    }
    if (t == 255) bsum[b] = lds[255];
}

__global__ __launch_bounds__(128) void k_gscan2(int* bsum, int nblk) {
    __shared__ int lds[128];
    int t = threadIdx.x;
    int v = (t < nblk) ? bsum[t] : 0;
    lds[t] = v;
    __syncthreads();
    for (int off = 1; off < 128; off <<= 1) {
        int tmp = (t >= off) ? lds[t - off] : 0;
        __syncthreads();
        lds[t] += tmp;
        __syncthreads();
    }
    if (t < nblk) bsum[t] = lds[t] - v;  // exclusive
}

__global__ void k_gscan3(int* __restrict__ ex, const int* __restrict__ bsum, int n) {
    int i = blockIdx.x * blockDim.x + threadIdx.x;
    if (i < n) ex[i] += bsum[i >> 10];
}

// ---------------------------------------------------------------------------
// P3: partition edges into per-(block,bucket) contiguous runs (LDS cursors only)
__global__ __launch_bounds__(256) void k_part(const void* ei, const int* __restrict__ flag,
                                              const int* __restrict__ off,
                                              unsigned* __restrict__ packed) {
    __shared__ int cur[K_B];
    int b = blockIdx.x;
    for (int i = threadIdx.x; i < K_B; i += 256) cur[i] = off[i * B_P + b];
    __syncthreads();
    int is32 = *flag;
    int e0 = b * CH, e1 = min(e0 + CH, NE);
    for (int e = e0 + threadIdx.x; e < e1; e += 256) {
        int s, d;
        load_edge(ei, is32, e, s, d);
        int k = d >> 8;
        int pos = atomicAdd(&cur[k], 1);
        packed[pos] = ((unsigned)s << 8) | (unsigned)(d & 255);
    }
}

// ---------------------------------------------------------------------------
// P4 fused per-bucket: count -> local scan -> rowptr/dinv/xn -> place ssrc.
__global__ __launch_bounds__(256) void k_bucket(const int* __restrict__ off,
                                                const unsigned* __restrict__ packed,
                                                const float* __restrict__ x,
                                                int* __restrict__ rowptr,
                                                float* __restrict__ dinv,
                                                float2* __restrict__ xn,
                                                int* __restrict__ ssrc) {
    __shared__ int cnt[256];
    __shared__ int excl[256];
    int k = blockIdx.x, t = threadIdx.x;
    cnt[t] = 0;
    __syncthreads();
    int g0 = off[k * B_P];
    int g1 = (k == K_B - 1) ? NE : off[(k + 1) * B_P];
    for (int i = g0 + t; i < g1; i += 256)
        atomicAdd(&cnt[packed[i] & 255u], 1);
    __syncthreads();
    int v = cnt[t];
    excl[t] = v;
    __syncthreads();
    for (int o = 1; o < 256; o <<= 1) {
        int tmp = (t >= o) ? excl[t - o] : 0;
        __syncthreads();
        excl[t] += tmp;
        __syncthreads();
    }
    int rb = g0 + excl[t] - v;  // rowptr[n]: bucket start + local exclusive prefix
    int n = (k << 8) + t;
    if (n < NN) {
        rowptr[n] = rb;
        float di = rsqrtf((float)(v + 1));  // +1 self-loop
        dinv[n] = di;
        float2 xv = ((const float2*)x)[n];
        xn[n] = make_float2(xv.x * di, xv.y * di);
    }
    if (k == K_B - 1 && t == 0) rowptr[NN] = NE;
    __syncthreads();
    excl[t] = rb;   // reuse as row base for placement
    cnt[t] = 0;
    __syncthreads();
    for (int i = g0 + t; i < g1; i += 256) {
        unsigned pk = packed[i];
        int dl = pk & 255u;
        int r = atomicAdd(&cnt[dl], 1);
        ssrc[excl[dl] + r] = (int)(pk >> 8);
    }
}

// ---------------------------------------------------------------------------
// Layer 1: 4 nodes per wave, 16 lanes per node (fixes 73% lane idleness of
// the 1-node/wave version: deg~16 means 48+ of 64 lanes used to sit idle).
// Per group: edges strided by 16, butterfly reduce within the 16-lane group,
// then 4 broadcast epilogues do the 2->64 transform with full-wave writes.
// hn1[n][j] = fp32( dinv[n]*relu(dinv[n]*agg . W1col_j + b1_j) )
__global__ __launch_bounds__(256) void k_layer1(const int* __restrict__ rowptr,
                                                const int* __restrict__ ssrc,
                                                const float2* __restrict__ xn,
                                                const float* __restrict__ dinv,
                                                const float* __restrict__ W1,
                                                const float* __restrict__ b1,
                                                float* __restrict__ hn1) {
    int w = threadIdx.x >> 6, lane = threadIdx.x & 63;
    int grp = lane >> 4, sub = lane & 15;
    int nbase = blockIdx.x * 16 + w * 4;      // grid exact: 6250*16 = NN
    int node = nbase + grp;
    int s0 = rowptr[node], e0 = rowptr[node + 1];
    float ax = 0.f, ay = 0.f;
    for (int i = s0 + sub; i < e0; i += 16) {
        float2 v = xn[ssrc[i]];
        ax += v.x; ay += v.y;
    }
#pragma unroll
    for (int m = 1; m < 16; m <<= 1) {        // reduce within 16-lane group
        ax += __shfl_xor(ax, m, 64);
        ay += __shfl_xor(ay, m, 64);
    }
#pragma unroll
    for (int c = 0; c < 4; ++c) {             // 4 transform epilogues
        float axc = __shfl(ax, c * 16, 64);   // group c's sum -> all lanes
        float ayc = __shfl(ay, c * 16, 64);
        int nc = nbase + c;
        float2 a = xn[nc];                    // self loop
        float di = dinv[nc];
        float axn = (axc + a.x) * di;
        float ayn = (ayc + a.y) * di;
        float v = fmaf(axn, W1[lane], fmaf(ayn, W1[64 + lane], b1[lane]));
        hn1[(size_t)nc * 64 + lane] = di * fmaxf(v, 0.f);
    }
}

// ---------------------------------------------------------------------------
// Dense transform tn1 = hn1 @ W2 (fp16 out), LANE = NODE mapping:
// each thread owns one node's row (float4 loads) and 64 fp32 accumulators;
// W2 read ROW-wise at wave-uniform addresses (scalarized). No LDS.
__global__ __launch_bounds__(256) void k_gemmW2(const float* __restrict__ hn1,
                                                const float* __restrict__ W2,
                                                __half* __restrict__ tn1) {
    int node = blockIdx.x * 256 + threadIdx.x;
    if (node >= NN) return;
    const float4* hp = (const float4*)(hn1 + (size_t)node * 64);
    float acc[64];
#pragma unroll
    for (int j = 0; j < 64; ++j) acc[j] = 0.f;
    for (int kc = 0; kc < 16; ++kc) {            // NOT unrolled: keep I$ small
        float4 h4 = hp[kc];
        const float* wr0 = W2 + (4 * kc + 0) * 64;   // wave-uniform rows
        const float* wr1 = W2 + (4 * kc + 1) * 64;
        const float* wr2 = W2 + (4 * kc + 2) * 64;
        const float* wr3 = W2 + (4 * kc + 3) * 64;
#pragma unroll
        for (int j = 0; j < 64; ++j) {
            float a = acc[j];
            a = fmaf(h4.x, wr0[j], a);
            a = fmaf(h4.y, wr1[j], a);
            a = fmaf(h4.z, wr2[j], a);
            a = fmaf(h4.w, wr3[j], a);
            acc[j] = a;
        }
    }
    __half2* op = (__half2*)(tn1 + (size_t)node * 64);
#pragma unroll
    for (int jp = 0; jp < 32; ++jp)
        op[jp] = __floats2half2_rn(acc[2 * jp], acc[2 * jp + 1]);
}

// ---------------------------------------------------------------------------
// Layer 2+3a aggregate, 2 nodes per wave with a COMBINED edge list:
// wave walks d0+d1 edges with a wave-uniform select, unroll 4 -> always 4
// independent gathers in flight regardless of degree imbalance. Epilogue
// (bias+ReLU+dinv, dot W3, butterfly) runs twice, all-register. No LDS.
__global__ __launch_bounds__(256) void k_layer2agg(const int* __restrict__ rowptr,
                                                   const int* __restrict__ ssrc,
                                                   const __half* __restrict__ tn1,
                                                   const float* __restrict__ dinv,
                                                   const float* __restrict__ b2,
                                                   const float* __restrict__ W3,
                                                   float* __restrict__ t3) {
    int w = threadIdx.x >> 6, lane = threadIdx.x & 63;
    int n0 = blockIdx.x * 8 + w * 2;          // grid exact: 12500*8 = NN
    int n1 = n0 + 1;
    int s0 = rowptr[n0], e0 = rowptr[n0 + 1], e1 = rowptr[n0 + 2];
    int s1 = e0;                              // consecutive rows share bounds
    int d0 = e0 - s0, tot = e1 - s0;          // d0 + d1 combined
    float a0 = __half2float(tn1[(size_t)n0 * 64 + lane]);  // self loops
    float a1 = __half2float(tn1[(size_t)n1 * 64 + lane]);
    int j = 0;
    for (; j + 4 <= tot; j += 4) {
#pragma unroll
        for (int u = 0; u < 4; ++u) {
            int jj = j + u;                   // wave-uniform slot
            float v = __half2float(tn1[(size_t)ssrc[s0 + jj] * 64 + lane]);
            if (jj < d0) a0 += v; else a1 += v;   // uniform branch
        }
    }
    for (; j < tot; ++j) {
        float v = __half2float(tn1[(size_t)ssrc[s0 + j] * 64 + lane]);
        if (j < d0) a0 += v; else a1 += v;
    }
    float w3 = W3[lane], bb = b2[lane];
    float di0 = dinv[n0];
    float r0 = di0 * fmaxf(fmaf(di0, a0, bb), 0.f) * w3;
    float di1 = dinv[n1];
    float r1 = di1 * fmaxf(fmaf(di1, a1, bb), 0.f) * w3;
#pragma unroll
    for (int m = 1; m < 64; m <<= 1) {
        r0 += __shfl_xor(r0, m, 64);
        r1 += __shfl_xor(r1, m, 64);
    }
    if (lane == 0) { t3[n0] = r0; t3[n1] = r1; }
}

// Scalar last layer: out[n] = dinv[n]*(t3[n] + sum t3[src]) + b3
__global__ void k_aggregate3(const int* __restrict__ rowptr, const int* __restrict__ ssrc,
                             const float* __restrict__ t3, const float* __restrict__ dinv,
                             const float* __restrict__ b3, float* __restrict__ out) {
    int n = blockIdx.x * blockDim.x + threadIdx.x;
    if (n >= NN) return;
    int s = rowptr[n], e = rowptr[n + 1];
    float acc = t3[n];
    int i = s;
    for (; i + 4 <= e; i += 4)
        acc += t3[ssrc[i]] + t3[ssrc[i + 1]] + t3[ssrc[i + 2]] + t3[ssrc[i + 3]];
    for (; i < e; ++i) acc += t3[ssrc[i]];
    out[n] = dinv[n] * acc + b3[0];
}

// ---------------------------------------------------------------------------
extern "C" void kernel_launch(void* const* d_in, const int* in_sizes, int n_in,
                              void* d_out, int out_size, void* d_ws, size_t ws_size,
                              hipStream_t stream) {
    const float* x  = (const float*)d_in[0];
    const void*  ei = d_in[1];
    const float* W1 = (const float*)d_in[2];
    const float* b1 = (const float*)d_in[3];
    const float* W2 = (const float*)d_in[4];
    const float* b2 = (const float*)d_in[5];
    const float* W3 = (const float*)d_in[6];
    const float* b3 = (const float*)d_in[7];
    float* out = (float*)d_out;

    char* ws = (char*)d_ws;
    size_t off_b = 0;
    auto take = [&](size_t bytes) -> char* {
        char* p = ws + off_b;
        off_b = (off_b + bytes + 255) & ~(size_t)255;
        return p;
    };
    float*    dinv   = (float*)take((size_t)NN * 4);
    int*      flag   = (int*)take(4);
    int*      bsum   = (int*)take(128 * 4);
    int*      rowptr = (int*)take((size_t)(NN + 1) * 4);
    int*      hist   = (int*)take((size_t)NSC * 4);
    int*      histS  = (int*)take((size_t)NSC * 4);
    unsigned* packed = (unsigned*)take((size_t)NE * 4);
    int*      ssrc   = (int*)take((size_t)NE * 4);
    float2*   xn     = (float2*)take((size_t)NN * 8);
    float*    hn1    = (float*)take((size_t)NN * 64 * 4);
    __half*   tn1    = (__half*)take((size_t)NN * 64 * 2);
    float*    t3     = (float*)take((size_t)NN * 4);

    // --- edge dtype detect ---
    hipMemsetAsync(flag, 0, 4, stream);
    k_detect<<<256, 256, 0, stream>>>((const unsigned int*)ei, flag);

    // --- atomic-free radix partition by dst (coarse buckets of 256 nodes) ---
    k_hist<<<B_P, 256, 0, stream>>>(ei, flag, hist);
    k_gscan1<<<NBLK_H, 256, 0, stream>>>(hist, histS, bsum, NSC);
    k_gscan2<<<1, 128, 0, stream>>>(bsum, NBLK_H);
    k_gscan3<<<(NSC + 255) / 256, 256, 0, stream>>>(histS, bsum, NSC);
    k_part<<<B_P, 256, 0, stream>>>(ei, flag, histS, packed);

    // --- fused per-bucket: count + scan -> rowptr/dinv/xn + place ssrc ---
    k_bucket<<<K_B, 256, 0, stream>>>(histS, packed, x, rowptr, dinv, xn, ssrc);

    // --- layer 1 (4 nodes/wave, 16 lanes/node, fp32 out) ---
    k_layer1<<<(NN + 15) / 16, 256, 0, stream>>>(rowptr, ssrc, xn, dinv, W1, b1, hn1);

    // --- dense 64x64 transform (lane=node, VALU-only matvec) ---
    k_gemmW2<<<(NN + 255) / 256, 256, 0, stream>>>(hn1, W2, tn1);

    // --- layer 2 aggregate (2 nodes/wave combined list) + epilogue + W3 dot ---
    k_layer2agg<<<(NN + 7) / 8, 256, 0, stream>>>(rowptr, ssrc, tn1, dinv, b2, W3, t3);

    // --- layer 3b (scalar aggregate) ---
    k_aggregate3<<<(NN + 255) / 256, 256, 0, stream>>>(rowptr, ssrc, t3, dinv, b3, out);
}

// Round 16
// 144.865 us; speedup vs baseline: 1.5192x; 1.1669x over previous
//
#include <hip/hip_runtime.h>
#include <hip/hip_fp16.h>

#define NN 100000
#define NE 1600000

// Radix partition params: buckets of 256 nodes
#define K_B 391                          // ceil(NN/256) buckets
#define B_P 250                          // partition blocks
#define CH  6400                         // edges per partition block (4-aligned)
#define CH4 (CH / 4)                     // 4-edge chunks per block
#define NSC (K_B * B_P)                  // histogram table size (97750)
#define NBLK_H ((NSC + 1023) / 1024)     // blocks for hist scan

// ---------------------------------------------------------------------------
// edge_index dtype detection: if int64 (values < 2^31), odd 32-bit words are 0.
__global__ void k_detect(const unsigned int* w, int* flag) {
    int i = blockIdx.x * blockDim.x + threadIdx.x;
    if (i < 65536 && w[2 * i + 1] != 0u) *flag = 1;
}

// ---------------------------------------------------------------------------
// P1: per-block histogram of dst>>8 (vectorized: 4 edges per thread-iter)
__global__ __launch_bounds__(256) void k_hist(const void* ei, const int* __restrict__ flag,
                                              int* __restrict__ hist) {
    __shared__ int h[K_B];
    for (int i = threadIdx.x; i < K_B; i += 256) h[i] = 0;
    __syncthreads();
    int b = blockIdx.x;
    int is32 = *flag;
    for (int c = threadIdx.x; c < CH4; c += 256) {
        int e = (b * CH4 + c) * 4;
        int d0, d1, d2, d3;
        if (is32) {
            int4 d4 = *(const int4*)((const int*)ei + NE + e);
            d0 = d4.x; d1 = d4.y; d2 = d4.z; d3 = d4.w;
        } else {
            const long long* p = (const long long*)ei + NE + e;
            d0 = (int)p[0]; d1 = (int)p[1]; d2 = (int)p[2]; d3 = (int)p[3];
        }
        atomicAdd(&h[d0 >> 8], 1);
        atomicAdd(&h[d1 >> 8], 1);
        atomicAdd(&h[d2 >> 8], 1);
        atomicAdd(&h[d3 >> 8], 1);
    }
    __syncthreads();
    for (int i = threadIdx.x; i < K_B; i += 256) hist[i * B_P + b] = h[i];
}

// ---------------------------------------------------------------------------
// Generalized hierarchical exclusive scan (3 kernels), n <= 128*1024
__global__ __launch_bounds__(256) void k_gscan1(const int* __restrict__ in,
                                                int* __restrict__ ex,
                                                int* __restrict__ bsum, int n) {
    __shared__ int lds[256];
    int b = blockIdx.x, t = threadIdx.x;
    int base = b * 1024 + t * 4;
    int v[4];
#pragma unroll
    for (int k = 0; k < 4; ++k) { int i = base + k; v[k] = (i < n) ? in[i] : 0; }
    int s = v[0] + v[1] + v[2] + v[3];
    lds[t] = s;
    __syncthreads();
    for (int off = 1; off < 256; off <<= 1) {
        int tmp = (t >= off) ? lds[t - off] : 0;
        __syncthreads();
        lds[t] += tmp;
        __syncthreads();
    }
    int run = lds[t] - s;
#pragma unroll
    for (int k = 0; k < 4; ++k) {
        int i = base + k;
        if (i < n) ex[i] = run;
        run += v[k];
    }
    if (t == 255) bsum[b] = lds[255];
}

__global__ __launch_bounds__(128) void k_gscan2(int* bsum, int nblk) {
    __shared__ int lds[128];
    int t = threadIdx.x;
    int v = (t < nblk) ? bsum[t] : 0;
    lds[t] = v;
    __syncthreads();
    for (int off = 1; off < 128; off <<= 1) {
        int tmp = (t >= off) ? lds[t - off] : 0;
        __syncthreads();
        lds[t] += tmp;
        __syncthreads();
    }
    if (t < nblk) bsum[t] = lds[t] - v;  // exclusive
}

__global__ void k_gscan3(int* __restrict__ ex, const int* __restrict__ bsum, int n) {
    int i = blockIdx.x * blockDim.x + threadIdx.x;
    if (i < n) ex[i] += bsum[i >> 10];
}

// ---------------------------------------------------------------------------
// P3: partition edges into per-(block,bucket) runs (LDS cursors, 4 edges/iter)
__global__ __launch_bounds__(256) void k_part(const void* ei, const int* __restrict__ flag,
                                              const int* __restrict__ off,
                                              unsigned* __restrict__ packed) {
    __shared__ int cur[K_B];
    int b = blockIdx.x;
    for (int i = threadIdx.x; i < K_B; i += 256) cur[i] = off[i * B_P + b];
    __syncthreads();
    int is32 = *flag;
    for (int c = threadIdx.x; c < CH4; c += 256) {
        int e = (b * CH4 + c) * 4;
        int s[4], d[4];
        if (is32) {
            int4 s4 = *(const int4*)((const int*)ei + e);
            int4 d4 = *(const int4*)((const int*)ei + NE + e);
            s[0] = s4.x; s[1] = s4.y; s[2] = s4.z; s[3] = s4.w;
            d[0] = d4.x; d[1] = d4.y; d[2] = d4.z; d[3] = d4.w;
        } else {
            const long long* ps = (const long long*)ei + e;
            const long long* pd = (const long long*)ei + NE + e;
#pragma unroll
            for (int u = 0; u < 4; ++u) { s[u] = (int)ps[u]; d[u] = (int)pd[u]; }
        }
#pragma unroll
        for (int u = 0; u < 4; ++u) {
            int k = d[u] >> 8;
            int pos = atomicAdd(&cur[k], 1);
            packed[pos] = ((unsigned)s[u] << 8) | (unsigned)(d[u] & 255);
        }
    }
}

// ---------------------------------------------------------------------------
// P4 fused per-bucket: count -> local scan -> rowptr/dinv/xn -> place ssrc.
__global__ __launch_bounds__(256) void k_bucket(const int* __restrict__ off,
                                                const unsigned* __restrict__ packed,
                                                const float* __restrict__ x,
                                                int* __restrict__ rowptr,
                                                float* __restrict__ dinv,
                                                float2* __restrict__ xn,
                                                int* __restrict__ ssrc) {
    __shared__ int cnt[256];
    __shared__ int excl[256];
    int k = blockIdx.x, t = threadIdx.x;
    cnt[t] = 0;
    __syncthreads();
    int g0 = off[k * B_P];
    int g1 = (k == K_B - 1) ? NE : off[(k + 1) * B_P];
    for (int i = g0 + t; i < g1; i += 256)
        atomicAdd(&cnt[packed[i] & 255u], 1);
    __syncthreads();
    int v = cnt[t];
    excl[t] = v;
    __syncthreads();
    for (int o = 1; o < 256; o <<= 1) {
        int tmp = (t >= o) ? excl[t - o] : 0;
        __syncthreads();
        excl[t] += tmp;
        __syncthreads();
    }
    int rb = g0 + excl[t] - v;  // rowptr[n]: bucket start + local exclusive prefix
    int n = (k << 8) + t;
    if (n < NN) {
        rowptr[n] = rb;
        float di = rsqrtf((float)(v + 1));  // +1 self-loop
        dinv[n] = di;
        float2 xv = ((const float2*)x)[n];
        xn[n] = make_float2(xv.x * di, xv.y * di);
    }
    if (k == K_B - 1 && t == 0) rowptr[NN] = NE;
    __syncthreads();
    excl[t] = rb;   // reuse as row base for placement
    cnt[t] = 0;
    __syncthreads();
    for (int i = g0 + t; i < g1; i += 256) {
        unsigned pk = packed[i];
        int dl = pk & 255u;
        int r = atomicAdd(&cnt[dl], 1);
        ssrc[excl[dl] + r] = (int)(pk >> 8);
    }
}

// ---------------------------------------------------------------------------
// Layer 1 + W2 fused: 4 nodes/wave 16-lane gather of xn, then per node the
// 2->64 transform (lane = feature) AND the 64x64 W2 matvec done in-wave:
// lane j holds h_j; t_l = sum_j readlane(h,j) * wc[j] with W2 column l held
// in 64 VGPRs (loaded once per wave). No LDS, no separate GEMM kernel, no
// fp32 hn1 round-trip.  tn1[n][l] = fp16( (hn1[n] @ W2)_l )
__global__ __launch_bounds__(256) void k_layer1(const int* __restrict__ rowptr,
                                                const int* __restrict__ ssrc,
                                                const float2* __restrict__ xn,
                                                const float* __restrict__ dinv,
                                                const float* __restrict__ W1,
                                                const float* __restrict__ b1,
                                                const float* __restrict__ W2,
                                                __half* __restrict__ tn1) {
    int w = threadIdx.x >> 6, lane = threadIdx.x & 63;
    float wc[64];
#pragma unroll
    for (int j = 0; j < 64; ++j) wc[j] = W2[j * 64 + lane];  // W2 column 'lane'
    float w1a = W1[lane], w1b = W1[64 + lane], bb = b1[lane];
    int grp = lane >> 4, sub = lane & 15;
    int nbase = blockIdx.x * 16 + w * 4;      // grid exact: 6250*16 = NN
    int node = nbase + grp;
    int s0 = rowptr[node], e0 = rowptr[node + 1];
    float ax = 0.f, ay = 0.f;
    for (int i = s0 + sub; i < e0; i += 16) {
        float2 v = xn[ssrc[i]];
        ax += v.x; ay += v.y;
    }
#pragma unroll
    for (int m = 1; m < 16; m <<= 1) {        // reduce within 16-lane group
        ax += __shfl_xor(ax, m, 64);
        ay += __shfl_xor(ay, m, 64);
    }
#pragma unroll
    for (int c = 0; c < 4; ++c) {             // 4 per-node epilogues
        float axc = __shfl(ax, c * 16, 64);
        float ayc = __shfl(ay, c * 16, 64);
        int nc = nbase + c;
        float2 a = xn[nc];                    // self loop
        float di = dinv[nc];
        float axn = (axc + a.x) * di;
        float ayn = (ayc + a.y) * di;
        float h = di * fmaxf(fmaf(axn, w1a, fmaf(ayn, w1b, bb)), 0.f);
        float t = 0.f;
#pragma unroll
        for (int j = 0; j < 64; ++j) {        // in-wave 64x64 matvec
            float hj = __uint_as_float(__builtin_amdgcn_readlane(__float_as_uint(h), j));
            t = fmaf(hj, wc[j], t);
        }
        tn1[(size_t)nc * 64 + lane] = __float2half(t);
    }
}

// ---------------------------------------------------------------------------
// Layer 2+3a aggregate, 2 nodes per wave with a COMBINED edge list, unroll 8:
// always 8 independent gathers in flight regardless of degree imbalance.
// Epilogue (bias+ReLU+dinv, dot W3, butterfly) all-register. No LDS.
__global__ __launch_bounds__(256) void k_layer2agg(const int* __restrict__ rowptr,
                                                   const int* __restrict__ ssrc,
                                                   const __half* __restrict__ tn1,
                                                   const float* __restrict__ dinv,
                                                   const float* __restrict__ b2,
                                                   const float* __restrict__ W3,
                                                   float* __restrict__ t3) {
    int w = threadIdx.x >> 6, lane = threadIdx.x & 63;
    int n0 = blockIdx.x * 8 + w * 2;          // grid exact: 12500*8 = NN
    int n1 = n0 + 1;
    int s0 = rowptr[n0], e0 = rowptr[n0 + 1], e1 = rowptr[n0 + 2];
    int d0 = e0 - s0, tot = e1 - s0;          // combined d0 + d1 edges
    float a0 = __half2float(tn1[(size_t)n0 * 64 + lane]);  // self loops
    float a1 = __half2float(tn1[(size_t)n1 * 64 + lane]);
    int j = 0;
    for (; j + 8 <= tot; j += 8) {
#pragma unroll
        for (int u = 0; u < 8; ++u) {
            int jj = j + u;                   // wave-uniform slot
            float v = __half2float(tn1[(size_t)ssrc[s0 + jj] * 64 + lane]);
            if (jj < d0) a0 += v; else a1 += v;   // uniform branch
        }
    }
    for (; j < tot; ++j) {
        float v = __half2float(tn1[(size_t)ssrc[s0 + j] * 64 + lane]);
        if (j < d0) a0 += v; else a1 += v;
    }
    float w3 = W3[lane], bb = b2[lane];
    float di0 = dinv[n0];
    float r0 = di0 * fmaxf(fmaf(di0, a0, bb), 0.f) * w3;
    float di1 = dinv[n1];
    float r1 = di1 * fmaxf(fmaf(di1, a1, bb), 0.f) * w3;
#pragma unroll
    for (int m = 1; m < 64; m <<= 1) {
        r0 += __shfl_xor(r0, m, 64);
        r1 += __shfl_xor(r1, m, 64);
    }
    if (lane == 0) { t3[n0] = r0; t3[n1] = r1; }
}

// Scalar last layer: out[n] = dinv[n]*(t3[n] + sum t3[src]) + b3
__global__ void k_aggregate3(const int* __restrict__ rowptr, const int* __restrict__ ssrc,
                             const float* __restrict__ t3, const float* __restrict__ dinv,
                             const float* __restrict__ b3, float* __restrict__ out) {
    int n = blockIdx.x * blockDim.x + threadIdx.x;
    if (n >= NN) return;
    int s = rowptr[n], e = rowptr[n + 1];
    float acc = t3[n];
    int i = s;
    for (; i + 4 <= e; i += 4)
        acc += t3[ssrc[i]] + t3[ssrc[i + 1]] + t3[ssrc[i + 2]] + t3[ssrc[i + 3]];
    for (; i < e; ++i) acc += t3[ssrc[i]];
    out[n] = dinv[n] * acc + b3[0];
}

// ---------------------------------------------------------------------------
extern "C" void kernel_launch(void* const* d_in, const int* in_sizes, int n_in,
                              void* d_out, int out_size, void* d_ws, size_t ws_size,
                              hipStream_t stream) {
    const float* x  = (const float*)d_in[0];
    const void*  ei = d_in[1];
    const float* W1 = (const float*)d_in[2];
    const float* b1 = (const float*)d_in[3];
    const float* W2 = (const float*)d_in[4];
    const float* b2 = (const float*)d_in[5];
    const float* W3 = (const float*)d_in[6];
    const float* b3 = (const float*)d_in[7];
    float* out = (float*)d_out;

    char* ws = (char*)d_ws;
    size_t off_b = 0;
    auto take = [&](size_t bytes) -> char* {
        char* p = ws + off_b;
        off_b = (off_b + bytes + 255) & ~(size_t)255;
        return p;
    };
    float*    dinv   = (float*)take((size_t)NN * 4);
    int*      flag   = (int*)take(4);
    int*      bsum   = (int*)take(128 * 4);
    int*      rowptr = (int*)take((size_t)(NN + 1) * 4);
    int*      hist   = (int*)take((size_t)NSC * 4);
    int*      histS  = (int*)take((size_t)NSC * 4);
    unsigned* packed = (unsigned*)take((size_t)NE * 4);
    int*      ssrc   = (int*)take((size_t)NE * 4);
    float2*   xn     = (float2*)take((size_t)NN * 8);
    __half*   tn1    = (__half*)take((size_t)NN * 64 * 2);
    float*    t3     = (float*)take((size_t)NN * 4);

    // --- edge dtype detect ---
    hipMemsetAsync(flag, 0, 4, stream);
    k_detect<<<256, 256, 0, stream>>>((const unsigned int*)ei, flag);

    // --- atomic-free radix partition by dst (coarse buckets of 256 nodes) ---
    k_hist<<<B_P, 256, 0, stream>>>(ei, flag, hist);
    k_gscan1<<<NBLK_H, 256, 0, stream>>>(hist, histS, bsum, NSC);
    k_gscan2<<<1, 128, 0, stream>>>(bsum, NBLK_H);
    k_gscan3<<<(NSC + 255) / 256, 256, 0, stream>>>(histS, bsum, NSC);
    k_part<<<B_P, 256, 0, stream>>>(ei, flag, histS, packed);

    // --- fused per-bucket: count + scan -> rowptr/dinv/xn + place ssrc ---
    k_bucket<<<K_B, 256, 0, stream>>>(histS, packed, x, rowptr, dinv, xn, ssrc);

    // --- layer 1 + W2 (4 nodes/wave gather, in-wave 64x64 matvec, fp16 out) ---
    k_layer1<<<(NN + 15) / 16, 256, 0, stream>>>(rowptr, ssrc, xn, dinv, W1, b1, W2, tn1);

    // --- layer 2 aggregate (2 nodes/wave, unroll 8) + epilogue + W3 dot ---
    k_layer2agg<<<(NN + 7) / 8, 256, 0, stream>>>(rowptr, ssrc, tn1, dinv, b2, W3, t3);

    // --- layer 3b (scalar aggregate) ---
    k_aggregate3<<<(NN + 255) / 256, 256, 0, stream>>>(rowptr, ssrc, t3, dinv, b3, out);
}